// Round 5
// baseline (97.054 us; speedup 1.0000x reference)
//
#include <hip/hip_runtime.h>

// Chamfer loss between subsampled point clouds.
// srcA: (64000,2) fp32 -> A = 8000 pts  (fp32 linspace trunc, matches jnp)
// srcB: (80000,2) fp32 -> B = 10000 pts
// out  = 0.5 * ( mean_i min_j |A_i - B_j| + mean_j min_i |A_i - B_j| )
//
// 3-op inner loop: d^2 = p^2 + (q^2 - 2 q.p); columns staged in LDS as
// float4 (-2qx, -2qy, qx^2+qy^2, 0). RPT=8 rows/thread so ONE
// ds_read_b128 broadcast feeds 24 VALU inst (48 cyc) -- DS pipe (<=12
// cyc/b128, shared per-CU) can no longer be the bottleneck (R4 post-
// mortem: RPT=4 put DS demand at 2x VALU demand -> LDS-issue-bound).
// CHUNK=64 keeps grid at 1253 blocks (~4.9 blocks/CU, ~20 waves/CU).
// Partial per-(row,chunk) d^2 mins direct-stored (no atomics, no init);
// 10.3 MB of partials stay L2-resident between the two dispatches.

#define SRC_A 64000
#define SRC_B 80000
#define NA 8000
#define NB 10000

#define BLOCK 256
#define CHUNK 64           // columns staged in LDS per block
#define RPT 8              // rows per thread
#define RPB (BLOCK * RPT)  // 2048 rows per block

#define NB1X 4    // ceil(8000/2048)
#define NB1Y 157  // ceil(10000/64)
#define NB2X 5    // ceil(10000/2048)
#define NB2Y 125  // ceil(8000/64)
#define NBLK1 (NB1X * NB1Y)   // 628
#define NBLK2 (NB2X * NB2Y)   // 625

#define P1_STRIDE (NB1X * RPB)            // 8192
#define P2_STRIDE (NB2X * RPB)            // 10240
#define P2_OFF_FLOATS (NB1Y * P1_STRIDE)  // 1286144 floats (~5.1 MB)

__global__ __launch_bounds__(BLOCK) void chamfer_partial(
        const float2* __restrict__ srcA, const float2* __restrict__ srcB,
        float* __restrict__ ws, float* __restrict__ out) {
    if (blockIdx.x == 0 && threadIdx.x == 0) *out = 0.0f;  // init for reduce's atomicAdd

    const bool pass1 = (int)blockIdx.x < NBLK1;
    const float2* srcRows; const float2* srcCols;
    float rowDelta, colDelta;
    int rowSrcMax, colSrcMax, nrows, ncols, bx, by, pstride;
    float* P;
    if (pass1) {
        int f = (int)blockIdx.x;
        bx = f % NB1X; by = f / NB1X;
        srcRows = srcA; rowDelta = (float)(SRC_A - 1) / (float)(NA - 1);
        rowSrcMax = SRC_A - 1; nrows = NA;
        srcCols = srcB; colDelta = (float)(SRC_B - 1) / (float)(NB - 1);
        colSrcMax = SRC_B - 1; ncols = NB;
        P = ws; pstride = P1_STRIDE;
    } else {
        int f = (int)blockIdx.x - NBLK1;
        bx = f % NB2X; by = f / NB2X;
        srcRows = srcB; rowDelta = (float)(SRC_B - 1) / (float)(NB - 1);
        rowSrcMax = SRC_B - 1; nrows = NB;
        srcCols = srcA; colDelta = (float)(SRC_A - 1) / (float)(NA - 1);
        colSrcMax = SRC_A - 1; ncols = NA;
        P = ws + P2_OFF_FLOATS; pstride = P2_STRIDE;
    }

    // stage column chunk as (-2qx, -2qy, qx^2+qy^2, 0)
    __shared__ float4 sc[CHUNK];
    int c0 = by * CHUNK;
    int cn = ncols - c0; if (cn > CHUNK) cn = CHUNK;
    int j = (int)threadIdx.x;
    if (j < cn) {
        int cidx = (int)((float)(c0 + j) * colDelta);
        if (cidx > colSrcMax) cidx = colSrcMax;
        float2 q = srcCols[cidx];
        sc[j] = make_float4(-2.0f * q.x, -2.0f * q.y,
                            fmaf(q.x, q.x, q.y * q.y), 0.0f);
    }
    __syncthreads();

    float2 p[RPT];
    float  p2[RPT];
    float  m[RPT];
    int r0 = bx * RPB + (int)threadIdx.x;
#pragma unroll
    for (int i = 0; i < RPT; ++i) {
        int r = r0 + i * BLOCK;
        int l = r < nrows ? r : nrows - 1;   // clamp for load; store is guarded
        int ridx = (int)((float)l * rowDelta);
        if (ridx > rowSrcMax) ridx = rowSrcMax;
        p[i]  = srcRows[ridx];
        p2[i] = fmaf(p[i].x, p[i].x, p[i].y * p[i].y);
        m[i]  = __builtin_inff();
    }

    int k = 0;
    for (; k + 2 <= cn; k += 2) {
        float4 q0 = sc[k + 0];
        float4 q1 = sc[k + 1];
#pragma unroll
        for (int i = 0; i < RPT; ++i) {
            float t0 = fmaf(q0.x, p[i].x, q0.z);
            t0 = fmaf(q0.y, p[i].y, t0);
            m[i] = fminf(m[i], t0);
            float t1 = fmaf(q1.x, p[i].x, q1.z);
            t1 = fmaf(q1.y, p[i].y, t1);
            m[i] = fminf(m[i], t1);
        }
    }
    if (k < cn) {
        float4 q = sc[k];
#pragma unroll
        for (int i = 0; i < RPT; ++i) {
            float t = fmaf(q.x, p[i].x, q.z);
            t = fmaf(q.y, p[i].y, t);
            m[i] = fminf(m[i], t);
        }
    }

#pragma unroll
    for (int i = 0; i < RPT; ++i) {
        int r = r0 + i * BLOCK;
        if (r < nrows) P[by * pstride + r] = m[i] + p2[i];  // partial min of d^2
    }
}

__global__ __launch_bounds__(BLOCK) void reduce_out(const float* __restrict__ ws,
                                                    float* __restrict__ out) {
    const float* P1 = ws;
    const float* P2 = ws + P2_OFF_FLOATS;
    float s = 0.0f;
    for (int t = (int)(blockIdx.x * BLOCK + threadIdx.x); t < NA + NB;
         t += (int)(gridDim.x * BLOCK)) {
        float mn = __builtin_inff();
        if (t < NA) {
#pragma unroll 4
            for (int c = 0; c < NB1Y; ++c) mn = fminf(mn, P1[c * P1_STRIDE + t]);
            s += sqrtf(fmaxf(mn, 0.0f)) * (0.5f / (float)NA);
        } else {
            int r = t - NA;
#pragma unroll 4
            for (int c = 0; c < NB2Y; ++c) mn = fminf(mn, P2[c * P2_STRIDE + r]);
            s += sqrtf(fmaxf(mn, 0.0f)) * (0.5f / (float)NB);
        }
    }
    for (int off = 32; off > 0; off >>= 1) s += __shfl_down(s, off, 64);
    __shared__ float red[4];
    int wave = (int)threadIdx.x >> 6;
    if ((threadIdx.x & 63) == 0) red[wave] = s;
    __syncthreads();
    if (threadIdx.x == 0) {
        float t = red[0] + red[1] + red[2] + red[3];
        atomicAdd(out, t);
    }
}

extern "C" void kernel_launch(void* const* d_in, const int* in_sizes, int n_in,
                              void* d_out, int out_size, void* d_ws, size_t ws_size,
                              hipStream_t stream) {
    (void)in_sizes; (void)n_in; (void)out_size; (void)ws_size;
    const float2* srcA = (const float2*)d_in[0];  // img_render_points (1000*64*2)
    const float2* srcB = (const float2*)d_in[1];  // ref point cloud (80000*2)
    float* ws = (float*)d_ws;
    float* out = (float*)d_out;

    chamfer_partial<<<NBLK1 + NBLK2, BLOCK, 0, stream>>>(srcA, srcB, ws, out);
    reduce_out<<<80, BLOCK, 0, stream>>>(ws, out);
}

// Round 6
// 90.780 us; speedup vs baseline: 1.0691x; 1.0691x over previous
//
#include <hip/hip_runtime.h>

// Chamfer loss between subsampled point clouds.
// srcA: (64000,2) fp32 -> A = 8000 pts  (fp32 linspace trunc, matches jnp)
// srcB: (80000,2) fp32 -> B = 10000 pts
// out  = 0.5 * ( mean_i min_j |A_i - B_j| + mean_j min_i |A_i - B_j| )
//
// R6: NO LDS in the hot loop. Column data is wave-uniform -> uniform-index
// float4 loads (s_load / single-txn broadcast via L1), removing the DS pipe
// and all barriers (R3-R5 evidence: LDS-staged variants plateau ~3-5x above
// the VALU floor regardless of DS tuning). A pregather dispatch materializes
// compact subsampled arrays once:
//   rows[t] = (px, py, px^2+py^2, 0)      cols[t] = (-2qx, -2qy, qx^2+qy^2, 0)
// so d^2 = p2 + fma(qy,py, fma(qx,px,q2)) -> 3 VALU/pair, p2 added at store.
// Main grid: 1280 blocks (~5/CU), 1024 rows/block (4/thread), 125-col
// chunks (exact: 80x125=10000, 64x125=8000), unroll 5. Partial d^2 mins
// direct-stored (no atomics/init); reduce kernel min-reduces, sqrt, means,
// atomicAdd into d_out (zeroed by pregather, stream-ordered).

#define SRC_A 64000
#define SRC_B 80000
#define NA 8000
#define NB 10000

#define BLOCK 256
#define RPT 4
#define RPB (BLOCK * RPT)      // 1024 rows per block
#define CCH 125                // columns per chunk

#define NB1X 8                 // ceil(8000/1024)
#define NB1Y 80                // 10000/125 exact
#define NB2X 10                // ceil(10000/1024)
#define NB2Y 64                // 8000/125 exact
#define NBLK1 (NB1X * NB1Y)    // 640
#define NBLK2 (NB2X * NB2Y)    // 640

#define P1_STRIDE (NB1X * RPB) // 8192
#define P2_STRIDE (NB2X * RPB) // 10240

// ---- ws layout (float offsets) ----
#define ROWSA_OFF 0            // float4[NA]   32000 floats
#define ROWSB_OFF 32000        // float4[NB]   40000 floats
#define COLSA_OFF 72000        // float4[NA]   32000 floats
#define COLSB_OFF 104000       // float4[NB]   40000 floats
#define P1_OFF    144000       // float[80*8192]  655360 floats
#define P2_OFF    799360       // float[64*10240] 655360 floats
                               // total 1454720 floats (~5.8 MB)

__global__ __launch_bounds__(BLOCK) void pregather(
        const float2* __restrict__ srcA, const float2* __restrict__ srcB,
        float* __restrict__ ws, float* __restrict__ out) {
    int t = (int)(blockIdx.x * BLOCK + threadIdx.x);
    if (t == 0) *out = 0.0f;   // init for reduce's atomicAdd
    float4* rowsA = (float4*)(ws + ROWSA_OFF);
    float4* rowsB = (float4*)(ws + ROWSB_OFF);
    float4* colsA = (float4*)(ws + COLSA_OFF);
    float4* colsB = (float4*)(ws + COLSB_OFF);
    if (t < NA) {
        float delta = (float)(SRC_A - 1) / (float)(NA - 1);
        int idx = (int)((float)t * delta);
        if (idx > SRC_A - 1) idx = SRC_A - 1;
        float2 p = srcA[idx];
        float p2 = fmaf(p.x, p.x, p.y * p.y);
        rowsA[t] = make_float4(p.x, p.y, p2, 0.0f);
        colsA[t] = make_float4(-2.0f * p.x, -2.0f * p.y, p2, 0.0f);
    }
    if (t < NB) {
        float delta = (float)(SRC_B - 1) / (float)(NB - 1);
        int idx = (int)((float)t * delta);
        if (idx > SRC_B - 1) idx = SRC_B - 1;
        float2 q = srcB[idx];
        float q2 = fmaf(q.x, q.x, q.y * q.y);
        rowsB[t] = make_float4(q.x, q.y, q2, 0.0f);
        colsB[t] = make_float4(-2.0f * q.x, -2.0f * q.y, q2, 0.0f);
    }
}

__global__ __launch_bounds__(BLOCK) void chamfer_main(const float* __restrict__ wsc,
                                                      float* __restrict__ wsp) {
    const bool pass1 = (int)blockIdx.x < NBLK1;
    const float4* rows; const float4* cols; float* P;
    int bx, by, nrows, pstride;
    if (pass1) {
        int f = (int)blockIdx.x;
        bx = f % NB1X; by = f / NB1X;
        rows = (const float4*)(wsc + ROWSA_OFF);
        cols = (const float4*)(wsc + COLSB_OFF);
        P = wsp + P1_OFF; nrows = NA; pstride = P1_STRIDE;
    } else {
        int f = (int)blockIdx.x - NBLK1;
        bx = f % NB2X; by = f / NB2X;
        rows = (const float4*)(wsc + ROWSB_OFF);
        cols = (const float4*)(wsc + COLSA_OFF);
        P = wsp + P2_OFF; nrows = NB; pstride = P2_STRIDE;
    }

    int r0 = bx * RPB + (int)threadIdx.x;
    float4 p[RPT];
    float  m[RPT];
#pragma unroll
    for (int i = 0; i < RPT; ++i) {
        int r = r0 + i * BLOCK;
        int l = r < nrows ? r : nrows - 1;   // clamp for load; store is guarded
        p[i] = rows[l];                       // coalesced 16B (compact array)
        m[i] = __builtin_inff();
    }

    int cbeg = by * CCH;
    for (int c = cbeg; c < cbeg + CCH; c += 5) {   // 25 iters, exact
#pragma unroll
        for (int u = 0; u < 5; ++u) {
            float4 q = cols[c + u];   // wave-uniform address: s_load / 1-txn broadcast
#pragma unroll
            for (int i = 0; i < RPT; ++i) {
                float t = fmaf(q.x, p[i].x, q.z);
                t = fmaf(q.y, p[i].y, t);
                m[i] = fminf(m[i], t);
            }
        }
    }

#pragma unroll
    for (int i = 0; i < RPT; ++i) {
        int r = r0 + i * BLOCK;
        if (r < nrows) P[by * pstride + r] = m[i] + p[i].z;  // partial min of d^2
    }
}

__global__ __launch_bounds__(BLOCK) void reduce_out(const float* __restrict__ ws,
                                                    float* __restrict__ out) {
    const float* P1 = ws + P1_OFF;
    const float* P2 = ws + P2_OFF;
    float s = 0.0f;
    for (int t = (int)(blockIdx.x * BLOCK + threadIdx.x); t < NA + NB;
         t += (int)(gridDim.x * BLOCK)) {
        float mn = __builtin_inff();
        if (t < NA) {
#pragma unroll 4
            for (int c = 0; c < NB1Y; ++c) mn = fminf(mn, P1[c * P1_STRIDE + t]);
            s += sqrtf(fmaxf(mn, 0.0f)) * (0.5f / (float)NA);
        } else {
            int r = t - NA;
#pragma unroll 4
            for (int c = 0; c < NB2Y; ++c) mn = fminf(mn, P2[c * P2_STRIDE + r]);
            s += sqrtf(fmaxf(mn, 0.0f)) * (0.5f / (float)NB);
        }
    }
    for (int off = 32; off > 0; off >>= 1) s += __shfl_down(s, off, 64);
    __shared__ float red[4];
    int wave = (int)threadIdx.x >> 6;
    if ((threadIdx.x & 63) == 0) red[wave] = s;
    __syncthreads();
    if (threadIdx.x == 0) {
        float t = red[0] + red[1] + red[2] + red[3];
        atomicAdd(out, t);
    }
}

extern "C" void kernel_launch(void* const* d_in, const int* in_sizes, int n_in,
                              void* d_out, int out_size, void* d_ws, size_t ws_size,
                              hipStream_t stream) {
    (void)in_sizes; (void)n_in; (void)out_size; (void)ws_size;
    const float2* srcA = (const float2*)d_in[0];  // img_render_points (1000*64*2)
    const float2* srcB = (const float2*)d_in[1];  // ref point cloud (80000*2)
    float* ws = (float*)d_ws;
    float* out = (float*)d_out;

    pregather<<<(NB + BLOCK - 1) / BLOCK, BLOCK, 0, stream>>>(srcA, srcB, ws, out);
    chamfer_main<<<NBLK1 + NBLK2, BLOCK, 0, stream>>>(ws, ws);
    reduce_out<<<80, BLOCK, 0, stream>>>(ws, out);
}

// Round 7
// 90.256 us; speedup vs baseline: 1.0753x; 1.0058x over previous
//
#include <hip/hip_runtime.h>

// Chamfer loss between subsampled point clouds.
// srcA: (64000,2) fp32 -> A = 8000 pts  (fp32 linspace trunc, matches jnp)
// srcB: (80000,2) fp32 -> B = 10000 pts
// out  = 0.5 * ( mean_i min_j |A_i - B_j| + mean_j min_i |A_i - B_j| )
//
// R7 model (from R1-R6 data): the hot loop is FETCH-pipe bound -- each wave
// re-fetches each column once, costing ~12 cyc/ds_read_b128 on the per-CU DS
// pipe (or the same on TA for global loads, which is why R6's no-LDS variant
// didn't help). Fetch cost per pair = 12/(64*RPT). RPT=8 balances DS demand
// with the 3-VALU-op/pair math (d^2 = p2 + fma(qy,py, fma(qx,px,q2))).
// R5's RPT=8 attempt regressed from confounds, mitigated here:
//   - CHUNK=100, exact tiling (100x100=10000, 80x100=8000): big chunks,
//     one barrier, no column tails.
//   - pregather dispatch materializes compact float4 arrays once:
//     rows=(px,py,p2,0), cols=(-2qx,-2qy,q2,0) -> coalesced dwordx4 row
//     loads instead of 64B-stride gathers repeated per block.
// Grid: 800 blocks (4x100 + 5x80), 2048 rows/block (8/thread). Partial
// per-(row,chunk) d^2 mins direct-stored (no atomics/init, ~6.6 MB
// L2-resident); reduce kernel min-reduces, sqrt, means, atomicAdd into
// d_out (zeroed by pregather, stream-ordered).

#define SRC_A 64000
#define SRC_B 80000
#define NA 8000
#define NB 10000

#define BLOCK 256
#define RPT 8
#define RPB (BLOCK * RPT)      // 2048 rows per block
#define CCH 100                // columns per chunk (exact divisor of both)

#define NB1X 4                 // ceil(8000/2048)
#define NB1Y 100               // 10000/100 exact
#define NB2X 5                 // ceil(10000/2048)
#define NB2Y 80                // 8000/100 exact
#define NBLK1 (NB1X * NB1Y)    // 400
#define NBLK2 (NB2X * NB2Y)    // 400

#define P1_STRIDE (NB1X * RPB) // 8192
#define P2_STRIDE (NB2X * RPB) // 10240

// ---- ws layout (float offsets) ----
#define ROWSA_OFF 0            // float4[NA]   32000 floats
#define ROWSB_OFF 32000        // float4[NB]   40000 floats
#define COLSA_OFF 72000        // float4[NA]   32000 floats
#define COLSB_OFF 104000       // float4[NB]   40000 floats
#define P1_OFF    144000       // float[100*8192]  819200 floats
#define P2_OFF    963200       // float[80*10240]  819200 floats
                               // total 1782400 floats (~7.1 MB)

__global__ __launch_bounds__(BLOCK) void pregather(
        const float2* __restrict__ srcA, const float2* __restrict__ srcB,
        float* __restrict__ ws, float* __restrict__ out) {
    int t = (int)(blockIdx.x * BLOCK + threadIdx.x);
    if (t == 0) *out = 0.0f;   // init for reduce's atomicAdd
    float4* rowsA = (float4*)(ws + ROWSA_OFF);
    float4* rowsB = (float4*)(ws + ROWSB_OFF);
    float4* colsA = (float4*)(ws + COLSA_OFF);
    float4* colsB = (float4*)(ws + COLSB_OFF);
    if (t < NA) {
        float delta = (float)(SRC_A - 1) / (float)(NA - 1);
        int idx = (int)((float)t * delta);
        if (idx > SRC_A - 1) idx = SRC_A - 1;
        float2 p = srcA[idx];
        float p2 = fmaf(p.x, p.x, p.y * p.y);
        rowsA[t] = make_float4(p.x, p.y, p2, 0.0f);
        colsA[t] = make_float4(-2.0f * p.x, -2.0f * p.y, p2, 0.0f);
    }
    if (t < NB) {
        float delta = (float)(SRC_B - 1) / (float)(NB - 1);
        int idx = (int)((float)t * delta);
        if (idx > SRC_B - 1) idx = SRC_B - 1;
        float2 q = srcB[idx];
        float q2 = fmaf(q.x, q.x, q.y * q.y);
        rowsB[t] = make_float4(q.x, q.y, q2, 0.0f);
        colsB[t] = make_float4(-2.0f * q.x, -2.0f * q.y, q2, 0.0f);
    }
}

__global__ __launch_bounds__(BLOCK) void chamfer_main(const float* __restrict__ ws) {
    const bool pass1 = (int)blockIdx.x < NBLK1;
    const float4* rows; const float4* cols; float* P;
    int bx, by, nrows, pstride;
    if (pass1) {
        int f = (int)blockIdx.x;
        bx = f % NB1X; by = f / NB1X;
        rows = (const float4*)(ws + ROWSA_OFF);
        cols = (const float4*)(ws + COLSB_OFF);
        P = (float*)(ws + P1_OFF); nrows = NA; pstride = P1_STRIDE;
    } else {
        int f = (int)blockIdx.x - NBLK1;
        bx = f % NB2X; by = f / NB2X;
        rows = (const float4*)(ws + ROWSB_OFF);
        cols = (const float4*)(ws + COLSA_OFF);
        P = (float*)(ws + P2_OFF); nrows = NB; pstride = P2_STRIDE;
    }

    // stage this block's 100 columns (already preprocessed) in LDS
    __shared__ float4 sc[CCH];
    int j = (int)threadIdx.x;
    if (j < CCH) sc[j] = cols[by * CCH + j];
    __syncthreads();

    int r0 = bx * RPB + (int)threadIdx.x;
    float4 p[RPT];
    float  m[RPT];
#pragma unroll
    for (int i = 0; i < RPT; ++i) {
        int r = r0 + i * BLOCK;
        int l = r < nrows ? r : nrows - 1;   // clamp for load; store is guarded
        p[i] = rows[l];                       // coalesced dwordx4 (compact array)
        m[i] = __builtin_inff();
    }

    // 50 iters x (2 ds_read_b128 broadcast + 48 VALU): DS ~= VALU demand
#pragma unroll 2
    for (int k = 0; k < CCH; k += 2) {
        float4 q0 = sc[k];
        float4 q1 = sc[k + 1];
#pragma unroll
        for (int i = 0; i < RPT; ++i) {
            float t0 = fmaf(q0.x, p[i].x, q0.z);
            t0 = fmaf(q0.y, p[i].y, t0);
            m[i] = fminf(m[i], t0);
        }
#pragma unroll
        for (int i = 0; i < RPT; ++i) {
            float t1 = fmaf(q1.x, p[i].x, q1.z);
            t1 = fmaf(q1.y, p[i].y, t1);
            m[i] = fminf(m[i], t1);
        }
    }

#pragma unroll
    for (int i = 0; i < RPT; ++i) {
        int r = r0 + i * BLOCK;
        if (r < nrows) P[by * pstride + r] = m[i] + p[i].z;  // partial min of d^2
    }
}

__global__ __launch_bounds__(BLOCK) void reduce_out(const float* __restrict__ ws,
                                                    float* __restrict__ out) {
    const float* P1 = ws + P1_OFF;
    const float* P2 = ws + P2_OFF;
    float s = 0.0f;
    for (int t = (int)(blockIdx.x * BLOCK + threadIdx.x); t < NA + NB;
         t += (int)(gridDim.x * BLOCK)) {
        float mn = __builtin_inff();
        if (t < NA) {
#pragma unroll 4
            for (int c = 0; c < NB1Y; ++c) mn = fminf(mn, P1[c * P1_STRIDE + t]);
            s += sqrtf(fmaxf(mn, 0.0f)) * (0.5f / (float)NA);
        } else {
            int r = t - NA;
#pragma unroll 4
            for (int c = 0; c < NB2Y; ++c) mn = fminf(mn, P2[c * P2_STRIDE + r]);
            s += sqrtf(fmaxf(mn, 0.0f)) * (0.5f / (float)NB);
        }
    }
    for (int off = 32; off > 0; off >>= 1) s += __shfl_down(s, off, 64);
    __shared__ float red[4];
    int wave = (int)threadIdx.x >> 6;
    if ((threadIdx.x & 63) == 0) red[wave] = s;
    __syncthreads();
    if (threadIdx.x == 0) {
        float t = red[0] + red[1] + red[2] + red[3];
        atomicAdd(out, t);
    }
}

extern "C" void kernel_launch(void* const* d_in, const int* in_sizes, int n_in,
                              void* d_out, int out_size, void* d_ws, size_t ws_size,
                              hipStream_t stream) {
    (void)in_sizes; (void)n_in; (void)out_size; (void)ws_size;
    const float2* srcA = (const float2*)d_in[0];  // img_render_points (1000*64*2)
    const float2* srcB = (const float2*)d_in[1];  // ref point cloud (80000*2)
    float* ws = (float*)d_ws;
    float* out = (float*)d_out;

    pregather<<<(NB + BLOCK - 1) / BLOCK, BLOCK, 0, stream>>>(srcA, srcB, ws, out);
    chamfer_main<<<NBLK1 + NBLK2, BLOCK, 0, stream>>>(ws);
    reduce_out<<<80, BLOCK, 0, stream>>>(ws, out);
}